// Round 3
// baseline (32.726 us; speedup 1.0000x reference)
//
#include <hip/hip_runtime.h>
#include <math.h>

namespace {
constexpr int B = 8, N = 1024, Q = 128, K = 16, M = N + Q;   // M = 1152
constexpr int WAVES_PER_BLOCK = 4;
constexpr int NWAVES = B * M;                     // 9216
constexpr int NBLOCKS = NWAVES / WAVES_PER_BLOCK; // 2304
}

#if __has_builtin(__builtin_amdgcn_exp2f)
  #define EXP2F(x) __builtin_amdgcn_exp2f(x)
#else
  #define EXP2F(x) exp2f(x)
#endif

__device__ __forceinline__ float sgpr_broadcast(float x) {
  return __uint_as_float(__builtin_amdgcn_readfirstlane(__float_as_uint(x)));
}

// ---------------------------------------------------------------------------
// One kernel. Threads 0-15 compute the fused per-kernel constants into LDS:
//   kern = exp(-(dx2*s0 + dy2*s1) / (tr * 2*bw^2)) = exp2(dx2*cA_k + dy2*cB_k)
// Then one wave per (b, m) output row; constants live in SGPRs.
// ---------------------------------------------------------------------------
__global__ __launch_bounds__(256, 8) void IvySPT_main(
    const float* __restrict__ lm_s, const float* __restrict__ ttm_s,
    const float* __restrict__ tv_s, const float* __restrict__ lm_q,
    const float* __restrict__ ttm_q, const float* __restrict__ lsk,
    const float* __restrict__ ln_s_w, const float* __restrict__ ln_s_b,
    const float* __restrict__ ln_q_w, const float* __restrict__ ln_q_b,
    const float* __restrict__ pls_p,
    float* __restrict__ out)
{
  __shared__ float sC[2][K];
  if (threadIdx.x < K) {
    const int k = threadIdx.x;
    float s0 = expf(lsk[2 * k + 0]);
    float s1 = expf(lsk[2 * k + 1]);
    float tr = s0 + s1;
    float x  = (float)(k + 1) / (float)(K + 1);
    float bw = erfinvf(x) * 1.41421356237309504880f;
    float denom = tr * 2.0f * bw * bw;
    const float LOG2E = 1.44269504088896340736f;
    sC[0][k] = -s0 * LOG2E / denom;
    sC[1][k] = -s1 * LOG2E / denom;
  }
  __syncthreads();

  const int lane = threadIdx.x & 63;
  const int wid  = threadIdx.x >> 6;
  const int w    = blockIdx.x * WAVES_PER_BLOCK + wid;   // 0 .. 9215
  const int b    = w / M;
  const int m    = w - b * M;

  // this row's coordinates (wave-uniform)
  float cmx, cmy;
  if (m < N) { cmx = lm_s[b * N + m];       cmy = ttm_s[b * N + m]; }
  else       { cmx = lm_q[b * Q + (m - N)]; cmy = ttm_q[b * Q + (m - N)]; }

  // fused per-k constants: wave-uniform -> force into SGPRs (frees 32 VGPRs;
  // v_mul/v_fma take 1 SGPR operand directly)
  float cA[K], cB[K];
#pragma unroll
  for (int k = 0; k < K; k++) {
    cA[k] = sgpr_broadcast(sC[0][k]);
    cB[k] = sgpr_broadcast(sC[1][k]);
  }

  float wsum[K], nrm[K];
#pragma unroll
  for (int k = 0; k < K; k++) { wsum[k] = 0.f; nrm[k] = 0.f; }

  const float2* xs2 = (const float2*)(lm_s  + b * N);
  const float2* ys2 = (const float2*)(ttm_s + b * N);
  const float2* tv2 = (const float2*)(tv_s  + b * N);

#pragma unroll 2
  for (int i = 0; i < N / 128; i++) {      // 8 iters, 2 n per lane per iter
    float2 sx = xs2[i * 64 + lane];
    float2 sy = ys2[i * 64 + lane];
    float2 t  = tv2[i * 64 + lane];
    float dx0 = cmx - sx.x, dx1 = cmx - sx.y;
    float dy0 = cmy - sy.x, dy1 = cmy - sy.y;
    float dx20 = dx0 * dx0, dx21 = dx1 * dx1;
    float dy20 = dy0 * dy0, dy21 = dy1 * dy1;
#pragma unroll
    for (int k = 0; k < K; k++) {
      float a0 = fmaf(dy20, cB[k], dx20 * cA[k]);
      float a1 = fmaf(dy21, cB[k], dx21 * cA[k]);
      float e0 = EXP2F(a0);
      float e1 = EXP2F(a1);
      wsum[k] = fmaf(e0, t.x, wsum[k]);
      nrm[k] += e0;
      wsum[k] = fmaf(e1, t.y, wsum[k]);
      nrm[k] += e1;
    }
  }

  // -------------------------------------------------------------------------
  // Wave-local reduction: LDS transpose [64][17] (pad -> only 2-way bank
  // aliasing, free), two passes. Per-wave slab; same-wave LDS ops are
  // ordered, explicit waitcnts are belt-and-braces.
  // -------------------------------------------------------------------------
  __shared__ float red[WAVES_PER_BLOCK][64][17];
  float (*rp)[17] = red[wid];
  const int col = lane & 15;
  const int qq  = lane >> 4;

  float totW, totN;
  {
#pragma unroll
    for (int c = 0; c < K; c++) rp[lane][c] = wsum[c];
    asm volatile("s_waitcnt lgkmcnt(0)" ::: "memory");
    float s = 0.f;
#pragma unroll
    for (int r = 0; r < 16; r++) s += rp[qq * 16 + r][col];
    asm volatile("s_waitcnt lgkmcnt(0)" ::: "memory");
    s += __shfl_xor(s, 16);
    s += __shfl_xor(s, 32);
    totW = s;
  }
  {
#pragma unroll
    for (int c = 0; c < K; c++) rp[lane][c] = nrm[c];
    asm volatile("s_waitcnt lgkmcnt(0)" ::: "memory");
    float s = 0.f;
#pragma unroll
    for (int r = 0; r < 16; r++) s += rp[qq * 16 + r][col];
    s += __shfl_xor(s, 16);
    s += __shfl_xor(s, 32);
    totN = s;
  }

  // Every lane now holds totals for k = lane & 15.
  float emb = totW / totN;

  // LayerNorm over K=16 within each 16-lane group
  float s1 = emb;
  s1 += __shfl_xor(s1, 1); s1 += __shfl_xor(s1, 2);
  s1 += __shfl_xor(s1, 4); s1 += __shfl_xor(s1, 8);
  float mean = s1 * (1.f / 16.f);
  float dv = emb - mean;
  float s2 = dv * dv;
  s2 += __shfl_xor(s2, 1); s2 += __shfl_xor(s2, 2);
  s2 += __shfl_xor(s2, 4); s2 += __shfl_xor(s2, 8);
  float inv = rsqrtf(s2 * (1.f / 16.f) + 1e-5f);

  const int k = col;
  float lw, lb;
  if (m < N) { lw = ln_s_w[k]; lb = ln_s_b[k]; }
  else       { lw = ln_q_w[k]; lb = ln_q_b[k]; }
  float normed = dv * inv * lw + lb;

  // Positional embedding: k = 4*i + c; c<2 -> x else y; c odd -> cos.
  float pls = pls_p[0];
  float invdiv = expf(-pls * (float)(k >> 2) * 0.25f);
  float cv  = (k & 2) ? cmy : cmx;
  float arg = cv * invdiv;
  float pe  = (k & 1) ? cosf(arg) : sinf(arg);
  float val = fmaf(pe, 1.41421356237309504880f, normed);

  if (lane < 16) out[((size_t)(b * M + m)) * K + k] = val;
}

extern "C" void kernel_launch(void* const* d_in, const int* in_sizes, int n_in,
                              void* d_out, int out_size, void* d_ws, size_t ws_size,
                              hipStream_t stream) {
  const float* lm_s   = (const float*)d_in[0];
  const float* ttm_s  = (const float*)d_in[1];
  const float* tv_s   = (const float*)d_in[2];
  const float* lm_q   = (const float*)d_in[3];
  const float* ttm_q  = (const float*)d_in[4];
  const float* lsk    = (const float*)d_in[5];
  const float* ln_s_w = (const float*)d_in[6];
  const float* ln_s_b = (const float*)d_in[7];
  const float* ln_q_w = (const float*)d_in[8];
  const float* ln_q_b = (const float*)d_in[9];
  const float* pls    = (const float*)d_in[10];

  float* out = (float*)d_out;

  hipLaunchKernelGGL(IvySPT_main, dim3(NBLOCKS), dim3(256), 0, stream,
                     lm_s, ttm_s, tv_s, lm_q, ttm_q, lsk,
                     ln_s_w, ln_s_b, ln_q_w, ln_q_b, pls, out);
}